// Round 3
// baseline (13301.537 us; speedup 1.0000x reference)
//
#include <hip/hip_runtime.h>
#include <math.h>

// JordanRNN B=128,T=2048,I=128,H=256,O=64.
// 16 WGs x 512 thr: 8 batch-columns x 2 hidden-halves. Each of 8 waves/WG owns a
// 16-unit slice (weights register-resident fp16; launch_bounds(512,1) -> 256 VGPR
// budget, no spills). One cross-WG MALL hop per step (partner h-half, 4KB).
// Wave 0 is sole publisher (release+flag) so waves 1-7 race into the next poll.
// 3 barriers per step.

#define TSTEPS 2048
#define ISZ 128

typedef _Float16 half8 __attribute__((ext_vector_type(8)));
typedef float f32x4 __attribute__((ext_vector_type(4)));
#define AGENT __HIP_MEMORY_SCOPE_AGENT

__device__ __forceinline__ f32x4 mfma16(half8 a, half8 b, f32x4 c) {
  return __builtin_amdgcn_mfma_f32_16x16x32_f16(a, b, c, 0, 0, 0);
}
__device__ __forceinline__ float sigm(float x) {
  return __builtin_amdgcn_rcpf(1.f + __expf(-x));
}
__device__ __forceinline__ float tanh_fast(float x) {
  return 1.f - 2.f * __builtin_amdgcn_rcpf(1.f + __expf(2.f * x));
}

// ws: payload [2 parity][16 wg][16 rows][128 halves] = 131072 B @0; flags u32[16] @131072

__global__ __launch_bounds__(512, 1)
void jordan_rnn(const float* __restrict__ xg, const float* __restrict__ w_ih,
                const float* __restrict__ w_hh, const float* __restrict__ b_ih,
                const float* __restrict__ b_hh, const float* __restrict__ fc_w,
                const float* __restrict__ fc_b, float* __restrict__ out,
                unsigned char* __restrict__ ws)
{
  const int tid  = threadIdx.x;
  const int lane = tid & 63;
  const int wv   = tid >> 6;          // wave 0..7
  const int n    = lane & 15;
  const int quad = lane >> 4;
  const int col  = blockIdx.x & 7;    // batch column (both halves same XCD: wg^8)
  const int p    = blockIdx.x >> 3;   // hidden half 0/1
  const int wg   = blockIdx.x;
  const int u0   = p * 128 + wv * 16; // this wave's unit slice (absolute in H)
  const int b0   = col * 16;

  unsigned char* pay = ws;
  unsigned int* flags = (unsigned int*)(ws + 131072);

  // act cols: 0..127 = x(t), 128..191 = y(t-1), 192..447 = h(t-1)/h(t)
  __shared__ _Float16 act[16][456];
  {
    unsigned int* za = (unsigned int*)&act[0][0];
    for (int i = tid; i < 3648; i += 512) za[i] = 0u;   // y,h regions must be 0
  }

  // ---- register-resident weights (fp16 B-fragments: lane holds W[n][k32+quad*8+q])
  half8 wr[14], wz[14], win[6], whn[8], wfc[8];
  {
    const int kq = quad * 8;
    const int ur = u0 + n, uz = 256 + u0 + n, un = 512 + u0 + n;
#pragma unroll
    for (int kk = 0; kk < 6; ++kk) {            // k 0..191: w_ih (x|y)
      const float* pr = w_ih + ur * 192 + kk * 32 + kq;
      const float* pz = w_ih + uz * 192 + kk * 32 + kq;
      const float* pn = w_ih + un * 192 + kk * 32 + kq;
#pragma unroll
      for (int q = 0; q < 8; ++q) {
        wr[kk][q] = (_Float16)pr[q]; wz[kk][q] = (_Float16)pz[q]; win[kk][q] = (_Float16)pn[q];
      }
    }
#pragma unroll
    for (int kk = 0; kk < 8; ++kk) {            // k 192..447: w_hh
      const float* pr = w_hh + ur * 256 + kk * 32 + kq;
      const float* pz = w_hh + uz * 256 + kk * 32 + kq;
      const float* pn = w_hh + un * 256 + kk * 32 + kq;
#pragma unroll
      for (int q = 0; q < 8; ++q) {
        wr[6 + kk][q] = (_Float16)pr[q]; wz[6 + kk][q] = (_Float16)pz[q]; whn[kk][q] = (_Float16)pn[q];
      }
    }
    if (wv < 4) {                               // y-waves: fc_w N-slice wv*16, ALL K
#pragma unroll
      for (int kk = 0; kk < 8; ++kk) {
        const float* pf = fc_w + (wv * 16 + n) * 256 + kk * 32 + kq;
#pragma unroll
        for (int q = 0; q < 8; ++q) wfc[kk][q] = (_Float16)pf[q];
      }
    }
  }
  const float br   = b_ih[u0 + n] + b_hh[u0 + n];
  const float bz   = b_ih[256 + u0 + n] + b_hh[256 + u0 + n];
  const float bin_ = b_ih[512 + u0 + n];
  const float bhn  = b_hh[512 + u0 + n];
  const float fcb  = (wv < 4) ? fc_b[wv * 16 + n] : 0.f;

  float hprev[4] = {0.f, 0.f, 0.f, 0.f};        // h(t-1) for (m=quad*4+r, u0+n), fp32
  f32x4 accy = {0.f, 0.f, 0.f, 0.f};            // own-half fc partial of y(t-1)
  __syncthreads();

  const int xm = tid >> 5, xp4 = tid & 31;      // x staging role (all 512)
  const int sm = tid >> 4, sq4 = tid & 15;      // partner-h stage role (tid<256)

  for (int t = 1; t <= TSTEPS; ++t) {
    // x(t-1) prefetch — in flight during the poll
    float4 xv = *(const float4*)(xg + ((size_t)(b0 + xm) * TSTEPS + (t - 1)) * (size_t)ISZ + xp4 * 4);

    // ---- single cross-WG hop: partner h(t-1)
    const unsigned int tgt = (unsigned int)(t - 1);
    if (t > 1) {
      while (__hip_atomic_load(&flags[wg ^ 8], __ATOMIC_RELAXED, AGENT) < tgt) {}
      __builtin_amdgcn_fence(__ATOMIC_ACQUIRE, "agent");
    }

    if (tid < 256) {
      const uint4* src = (const uint4*)(pay + (size_t)((t - 1) & 1) * 65536 + (size_t)(wg ^ 8) * 4096);
      uint4 v = src[sm * 16 + sq4];
      *(uint4*)&act[sm][192 + (p ^ 1) * 128 + sq4 * 8] = v;
    }
    {
      union { _Float16 h[4]; uint2 u; } pk;
      pk.h[0] = (_Float16)xv.x; pk.h[1] = (_Float16)xv.y;
      pk.h[2] = (_Float16)xv.z; pk.h[3] = (_Float16)xv.w;
      *(uint2*)&act[xm][xp4 * 4] = pk.u;
    }
    __syncthreads();  // S1: x + full h(t-1) staged

    // ---- finish y(t-1): partner-half fc MFMAs (own half already in accy)
    if (wv < 4) {
      const int kk0 = (p ^ 1) * 4;
#pragma unroll
      for (int kk = 0; kk < 4; ++kk) {
        half8 af = *(const half8*)&act[n][192 + (kk0 + kk) * 32 + quad * 8];
        accy = mfma16(af, wfc[kk0 + kk], accy);
      }
      if (t > 1) {
#pragma unroll
        for (int r = 0; r < 4; ++r)
          act[quad * 4 + r][128 + wv * 16 + n] = (_Float16)tanh_fast(accy[r] + fcb);
      }
      // t==1: y(0)=0 already in act from preamble
    }

    // ---- gate MFMAs not needing y: x (K0-3), h (K6-13)
    f32x4 aR = {0,0,0,0}, aZ = {0,0,0,0}, aIN = {0,0,0,0}, aHN = {0,0,0,0};
#pragma unroll
    for (int kk = 0; kk < 4; ++kk) {
      half8 af = *(const half8*)&act[n][kk * 32 + quad * 8];
      aR = mfma16(af, wr[kk], aR);
      aZ = mfma16(af, wz[kk], aZ);
      aIN = mfma16(af, win[kk], aIN);
    }
#pragma unroll
    for (int kk = 6; kk < 14; ++kk) {
      half8 af = *(const half8*)&act[n][kk * 32 + quad * 8];
      aR = mfma16(af, wr[kk], aR);
      aZ = mfma16(af, wz[kk], aZ);
      aHN = mfma16(af, whn[kk - 6], aHN);
    }
    __syncthreads();  // S2: y(t-1) staged (also orders h-region reads vs gating writes)
#pragma unroll
    for (int kk = 4; kk < 6; ++kk) {
      half8 af = *(const half8*)&act[n][kk * 32 + quad * 8];
      aR = mfma16(af, wr[kk], aR);
      aZ = mfma16(af, wz[kk], aZ);
      aIN = mfma16(af, win[kk], aIN);
    }

    // ---- gating (fp32) -> h(t) own slice into act (y-region reads kk4-5 are
    //      wave-local program-order before these h-region writes; no barrier needed)
#pragma unroll
    for (int r = 0; r < 4; ++r) {
      float rg = sigm(aR[r] + br);
      float zg = sigm(aZ[r] + bz);
      float nn = tanh_fast(aIN[r] + bin_ + rg * (aHN[r] + bhn));
      float hv = (1.f - zg) * nn + zg * hprev[r];
      hprev[r] = hv;
      act[quad * 4 + r][192 + u0 + n] = (_Float16)hv;
    }
    __syncthreads();  // S3: own half of h(t) complete in act

    // ---- wave 0: sole publisher of own h(t) half + release + flag.
    //      Waves 1-7 race ahead into next iteration's prefetch/poll.
    if (wv == 0) {
      unsigned int* dstb = (unsigned int*)(pay + (size_t)(t & 1) * 65536 + (size_t)wg * 4096);
#pragma unroll
      for (int i = 0; i < 4; ++i) {
        int d = lane + 64 * i;                   // 0..255 uint4 slots
        int m = d >> 4, q4 = d & 15;
        uint4 v = *(const uint4*)&act[m][192 + p * 128 + q4 * 8];
        unsigned int* dst = dstb + (m * 16 + q4) * 4;
        __hip_atomic_store(dst + 0, v.x, __ATOMIC_RELAXED, AGENT);
        __hip_atomic_store(dst + 1, v.y, __ATOMIC_RELAXED, AGENT);
        __hip_atomic_store(dst + 2, v.z, __ATOMIC_RELAXED, AGENT);
        __hip_atomic_store(dst + 3, v.w, __ATOMIC_RELAXED, AGENT);
      }
      if (lane == 0) { /* release drains wave 0's payload stores */ }
      __hip_atomic_store(&flags[wg], (unsigned int)t, __ATOMIC_RELEASE, AGENT);
    }

    // ---- own-half fc partial of y(t) (overlaps publish store-ack)
    if (wv < 4) {
      const int kk0 = p * 4;
      accy = (f32x4){0.f, 0.f, 0.f, 0.f};
#pragma unroll
      for (int kk = 0; kk < 4; ++kk) {
        half8 af = *(const half8*)&act[n][192 + (kk0 + kk) * 32 + quad * 8];
        accy = mfma16(af, wfc[kk0 + kk], accy);
      }
    }
  }

  // ---- epilogue: y(T) = tanh(fc @ h(T) + b); accy holds own-half partial
  while (__hip_atomic_load(&flags[wg ^ 8], __ATOMIC_RELAXED, AGENT) < (unsigned int)TSTEPS) {}
  __builtin_amdgcn_fence(__ATOMIC_ACQUIRE, "agent");
  if (tid < 256) {
    const uint4* src = (const uint4*)(pay + (size_t)(TSTEPS & 1) * 65536 + (size_t)(wg ^ 8) * 4096);
    uint4 v = src[sm * 16 + sq4];
    *(uint4*)&act[sm][192 + (p ^ 1) * 128 + sq4 * 8] = v;
  }
  __syncthreads();
  if (wv < 4 && p == 0) {                       // p==0 writes out (avoid dup-write race)
    const int kk0 = 4;                          // partner half for p=0
#pragma unroll
    for (int kk = 0; kk < 4; ++kk) {
      half8 af = *(const half8*)&act[n][192 + (kk0 + kk) * 32 + quad * 8];
      accy = mfma16(af, wfc[kk0 + kk], accy);
    }
#pragma unroll
    for (int r = 0; r < 4; ++r)
      out[(size_t)(b0 + quad * 4 + r) * 64 + wv * 16 + n] = tanh_fast(accy[r] + fcb);
  }
}

extern "C" void kernel_launch(void* const* d_in, const int* in_sizes, int n_in,
                              void* d_out, int out_size, void* d_ws, size_t ws_size,
                              hipStream_t stream) {
  hipMemsetAsync(d_ws, 0, 131136, stream);  // payload (h(0)=0) + flags ("step0 done")
  jordan_rnn<<<dim3(16), dim3(512), 0, stream>>>(
      (const float*)d_in[0], (const float*)d_in[1], (const float*)d_in[2],
      (const float*)d_in[3], (const float*)d_in[4], (const float*)d_in[5],
      (const float*)d_in[6], (float*)d_out, (unsigned char*)d_ws);
}

// Round 4
// 8373.013 us; speedup vs baseline: 1.5886x; 1.5886x over previous
//
#include <hip/hip_runtime.h>
#include <math.h>

// JordanRNN B=128,T=2048,I=128,H=256,O=64.
// 32 WGs x 256 thr (4 waves): 8 batch-columns x 4 hidden-quarters (64 units each;
// 4 waves x 16-unit slice, weights register-resident fp16, launch_bounds(256,1)
// -> 1 block/CU -> full VGPR budget, no spills). One MALL hop per step: poll 3
// partner flags, read 3x2KB partner h-quarters; wave0 publishes own 2KB + release.
// y computed redundantly per WG. 3 barriers/step. x prefetched one step ahead.

#define TSTEPS 2048
#define ISZ 128

typedef _Float16 half8 __attribute__((ext_vector_type(8)));
typedef float f32x4 __attribute__((ext_vector_type(4)));
#define AGENT __HIP_MEMORY_SCOPE_AGENT

__device__ __forceinline__ f32x4 mfma16(half8 a, half8 b, f32x4 c) {
  return __builtin_amdgcn_mfma_f32_16x16x32_f16(a, b, c, 0, 0, 0);
}
__device__ __forceinline__ float sigm(float x) {
  return __builtin_amdgcn_rcpf(1.f + __expf(-x));
}
__device__ __forceinline__ float tanh_fast(float x) {
  return 1.f - 2.f * __builtin_amdgcn_rcpf(1.f + __expf(2.f * x));
}

// ws: pay[2 parity][8 col][4 q][16 rows][64 units] fp16 = 131072 B @0
//     flags u32[8 col][4 q] = 128 B @131072

__global__ __launch_bounds__(256, 1)
void jordan_rnn(const float* __restrict__ xg, const float* __restrict__ w_ih,
                const float* __restrict__ w_hh, const float* __restrict__ b_ih,
                const float* __restrict__ b_hh, const float* __restrict__ fc_w,
                const float* __restrict__ fc_b, float* __restrict__ out,
                unsigned char* __restrict__ ws)
{
  const int tid  = threadIdx.x;
  const int lane = tid & 63;
  const int wv   = tid >> 6;          // wave 0..3
  const int n    = lane & 15;
  const int quad = lane >> 4;
  const int col  = blockIdx.x & 7;    // batch column; all 4 quarters same XCD
  const int q    = blockIdx.x >> 3;   // hidden quarter 0..3
  const int u0   = q * 64 + wv * 16;  // this wave's unit slice (absolute in H)
  const int b0   = col * 16;

  unsigned char* pay = ws;
  unsigned int* flags = (unsigned int*)(ws + 131072);

  // act cols: 0..127 = x(t-1), 128..191 = y(t-1), 192..447 = h
  __shared__ _Float16 act[16][456];
  {
    unsigned int* za = (unsigned int*)&act[0][0];
    for (int i = tid; i < 3648; i += 256) za[i] = 0u;   // y,h regions must start 0
  }

  // ---- register-resident weights (fp16 B-fragments: lane holds W[row=n][k32+quad*8+j])
  half8 wr[14], wz[14], win[6], whn[8], wfc[8];
  {
    const int kq = quad * 8;
    const int ur = u0 + n, uz = 256 + u0 + n, un = 512 + u0 + n;
#pragma unroll
    for (int kk = 0; kk < 6; ++kk) {            // k 0..191: w_ih (x|y)
      const float* pr = w_ih + ur * 192 + kk * 32 + kq;
      const float* pz = w_ih + uz * 192 + kk * 32 + kq;
      const float* pn = w_ih + un * 192 + kk * 32 + kq;
#pragma unroll
      for (int j = 0; j < 8; ++j) {
        wr[kk][j] = (_Float16)pr[j]; wz[kk][j] = (_Float16)pz[j]; win[kk][j] = (_Float16)pn[j];
      }
    }
#pragma unroll
    for (int kk = 0; kk < 8; ++kk) {            // k 192..447: w_hh
      const float* pr = w_hh + ur * 256 + kk * 32 + kq;
      const float* pz = w_hh + uz * 256 + kk * 32 + kq;
      const float* pn = w_hh + un * 256 + kk * 32 + kq;
#pragma unroll
      for (int j = 0; j < 8; ++j) {
        wr[6 + kk][j] = (_Float16)pr[j]; wz[6 + kk][j] = (_Float16)pz[j]; whn[kk][j] = (_Float16)pn[j];
      }
    }
#pragma unroll
    for (int kk = 0; kk < 8; ++kk) {            // fc: rows wv*16+n, all K
      const float* pf = fc_w + (wv * 16 + n) * 256 + kk * 32 + kq;
#pragma unroll
      for (int j = 0; j < 8; ++j) wfc[kk][j] = (_Float16)pf[j];
    }
  }
  const float br   = b_ih[u0 + n] + b_hh[u0 + n];
  const float bz   = b_ih[256 + u0 + n] + b_hh[256 + u0 + n];
  const float bin_ = b_ih[512 + u0 + n];
  const float bhn  = b_hh[512 + u0 + n];
  const float fcb  = fc_b[wv * 16 + n];

  float hprev[4] = {0.f, 0.f, 0.f, 0.f};
  f32x4 accy = {0.f, 0.f, 0.f, 0.f};            // own-quarter fc partial of y(t-1)
  __syncthreads();

  // roles
  const int xr = tid >> 4, xc = tid & 15;       // x: row, 2 float4s at xc*2(+1)
  const int pq0 = (q + 1) & 3, pq1 = (q + 2) & 3, pq2 = (q + 3) & 3;
  const int su = tid & 127;                      // partner-stage uint4 idx
  const int sm = su >> 3, sc = su & 7;
  const int fkk0 = q * 2;                        // own fc frag indices {fkk0, fkk0+1}

  // x(0) prefetch
  float4 xv0 = *(const float4*)(xg + ((size_t)(b0 + xr) * TSTEPS + 0) * ISZ + xc * 8);
  float4 xv1 = *(const float4*)(xg + ((size_t)(b0 + xr) * TSTEPS + 0) * ISZ + xc * 8 + 4);

  for (int t = 1; t <= TSTEPS; ++t) {
    const unsigned int tgt = (unsigned int)(t - 1);

    // ---- poll 3 partner flags (relaxed), then one acquire fence
    if (t > 1) {
      unsigned int f;
      do {
        f = (lane < 4 && lane != q)
              ? __hip_atomic_load(&flags[col * 4 + lane], __ATOMIC_RELAXED, AGENT)
              : 0xFFFFFFFFu;
      } while (!__all((int)(f >= tgt)));
      __builtin_amdgcn_fence(__ATOMIC_ACQUIRE, "agent");
    }

    // ---- stage partner h(t-1) quarters (3 x 2KB from MALL)
    {
      const uint4* pb = (const uint4*)(pay + (size_t)((t - 1) & 1) * 65536 + (size_t)col * 8192);
      const int qa = (tid < 128) ? pq0 : pq1;
      uint4 va = pb[qa * 128 + su];
      *(uint4*)&act[sm][192 + qa * 64 + sc * 8] = va;
      if (tid < 128) {
        uint4 vb = pb[pq2 * 128 + su];
        *(uint4*)&act[sm][192 + pq2 * 64 + sc * 8] = vb;
      }
    }
    // ---- stage x(t-1) (prefetched regs -> fp16 LDS)
    {
      union { _Float16 h[8]; uint4 u; } pk;
      pk.h[0] = (_Float16)xv0.x; pk.h[1] = (_Float16)xv0.y;
      pk.h[2] = (_Float16)xv0.z; pk.h[3] = (_Float16)xv0.w;
      pk.h[4] = (_Float16)xv1.x; pk.h[5] = (_Float16)xv1.y;
      pk.h[6] = (_Float16)xv1.z; pk.h[7] = (_Float16)xv1.w;
      *(uint4*)&act[xr][xc * 8] = pk.u;
    }
    // ---- prefetch x(t) for next step (full step to land; clamp at end)
    {
      const size_t ts = (t < TSTEPS) ? (size_t)t : (size_t)(TSTEPS - 1);
      const float* xp = xg + ((size_t)(b0 + xr) * TSTEPS + ts) * ISZ + xc * 8;
      xv0 = *(const float4*)xp;
      xv1 = *(const float4*)(xp + 4);
    }
    __syncthreads();  // S1: x + full h(t-1) staged

    // ---- finish y(t-1): partner-quarter fc MFMAs (own quarter already in accy)
#pragma unroll
    for (int kk = 0; kk < 8; ++kk) {
      if (kk == fkk0 || kk == fkk0 + 1) continue;
      half8 af = *(const half8*)&act[n][192 + kk * 32 + quad * 8];
      accy = mfma16(af, wfc[kk], accy);
    }
    if (t > 1) {
#pragma unroll
      for (int r = 0; r < 4; ++r)
        act[quad * 4 + r][128 + wv * 16 + n] = (_Float16)tanh_fast(accy[r] + fcb);
    }
    // t==1: y(0)=0 already in act

    // ---- gate MFMAs not needing y: x (K0-3), h (K6-13)
    f32x4 aR = {0,0,0,0}, aZ = {0,0,0,0}, aIN = {0,0,0,0}, aHN = {0,0,0,0};
#pragma unroll
    for (int kk = 0; kk < 4; ++kk) {
      half8 af = *(const half8*)&act[n][kk * 32 + quad * 8];
      aR = mfma16(af, wr[kk], aR);
      aZ = mfma16(af, wz[kk], aZ);
      aIN = mfma16(af, win[kk], aIN);
    }
#pragma unroll
    for (int kk = 6; kk < 14; ++kk) {
      half8 af = *(const half8*)&act[n][kk * 32 + quad * 8];
      aR = mfma16(af, wr[kk], aR);
      aZ = mfma16(af, wz[kk], aZ);
      aHN = mfma16(af, whn[kk - 6], aHN);
    }
    __syncthreads();  // S2: y(t-1) staged; all h-region reads done
#pragma unroll
    for (int kk = 4; kk < 6; ++kk) {
      half8 af = *(const half8*)&act[n][kk * 32 + quad * 8];
      aR = mfma16(af, wr[kk], aR);
      aZ = mfma16(af, wz[kk], aZ);
      aIN = mfma16(af, win[kk], aIN);
    }

    // ---- gating (fp32) -> own h(t) slice into act + hprev regs
#pragma unroll
    for (int r = 0; r < 4; ++r) {
      float rg = sigm(aR[r] + br);
      float zg = sigm(aZ[r] + bz);
      float nn = tanh_fast(aIN[r] + bin_ + rg * (aHN[r] + bhn));
      float hv = (1.f - zg) * nn + zg * hprev[r];
      hprev[r] = hv;
      act[quad * 4 + r][192 + u0 + n] = (_Float16)hv;
    }
    __syncthreads();  // S3: own quarter of h(t) complete in act

    // ---- wave0: publish own quarter + release flag (waves 1-3 race ahead)
    if (wv == 0) {
      unsigned int* dst = (unsigned int*)(pay + (size_t)(t & 1) * 65536
                                          + (size_t)col * 8192 + (size_t)q * 2048);
#pragma unroll
      for (int i = 0; i < 2; ++i) {
        int u = lane + 64 * i;                   // 0..127 uint4 slots
        int m = u >> 3, c = u & 7;
        uint4 v = *(const uint4*)&act[m][192 + q * 64 + c * 8];
        unsigned int* d4 = dst + u * 4;
        __hip_atomic_store(d4 + 0, v.x, __ATOMIC_RELAXED, AGENT);
        __hip_atomic_store(d4 + 1, v.y, __ATOMIC_RELAXED, AGENT);
        __hip_atomic_store(d4 + 2, v.z, __ATOMIC_RELAXED, AGENT);
        __hip_atomic_store(d4 + 3, v.w, __ATOMIC_RELAXED, AGENT);
      }
      if (lane == 0)
        __hip_atomic_store(&flags[col * 4 + q], (unsigned int)t, __ATOMIC_RELEASE, AGENT);
    }

    // ---- own-quarter fc partial of y(t) (overlaps publish ack)
    accy = (f32x4){0.f, 0.f, 0.f, 0.f};
#pragma unroll
    for (int kk = 0; kk < 2; ++kk) {
      half8 af = *(const half8*)&act[n][192 + (fkk0 + kk) * 32 + quad * 8];
      accy = mfma16(af, wfc[fkk0 + kk], accy);
    }
  }

  // ---- epilogue: y(T) = tanh(fc @ h(T) + b); accy holds own-quarter partial
  {
    const unsigned int tgt = (unsigned int)TSTEPS;
    unsigned int f;
    do {
      f = (lane < 4 && lane != q)
            ? __hip_atomic_load(&flags[col * 4 + lane], __ATOMIC_RELAXED, AGENT)
            : 0xFFFFFFFFu;
    } while (!__all((int)(f >= tgt)));
    __builtin_amdgcn_fence(__ATOMIC_ACQUIRE, "agent");
  }
  {
    const uint4* pb = (const uint4*)(pay + (size_t)(TSTEPS & 1) * 65536 + (size_t)col * 8192);
    const int qa = (tid < 128) ? pq0 : pq1;
    uint4 va = pb[qa * 128 + su];
    *(uint4*)&act[sm][192 + qa * 64 + sc * 8] = va;
    if (tid < 128) {
      uint4 vb = pb[pq2 * 128 + su];
      *(uint4*)&act[sm][192 + pq2 * 64 + sc * 8] = vb;
    }
  }
  __syncthreads();
  if (q == 0) {                                 // one WG per column writes out
#pragma unroll
    for (int kk = 0; kk < 8; ++kk) {
      if (kk == fkk0 || kk == fkk0 + 1) continue;
      half8 af = *(const half8*)&act[n][192 + kk * 32 + quad * 8];
      accy = mfma16(af, wfc[kk], accy);
    }
#pragma unroll
    for (int r = 0; r < 4; ++r)
      out[(size_t)(b0 + quad * 4 + r) * 64 + wv * 16 + n] = tanh_fast(accy[r] + fcb);
  }
}

extern "C" void kernel_launch(void* const* d_in, const int* in_sizes, int n_in,
                              void* d_out, int out_size, void* d_ws, size_t ws_size,
                              hipStream_t stream) {
  hipMemsetAsync(d_ws, 0, 131200, stream);  // payload (h(0)=0) + flags ("step 0 done")
  jordan_rnn<<<dim3(32), dim3(256), 0, stream>>>(
      (const float*)d_in[0], (const float*)d_in[1], (const float*)d_in[2],
      (const float*)d_in[3], (const float*)d_in[4], (const float*)d_in[5],
      (const float*)d_in[6], (float*)d_out, (unsigned char*)d_ws);
}